// Round 8
// baseline (4328.959 us; speedup 1.0000x reference)
//
#include <hip/hip_runtime.h>
#include <cstddef>
#include <cstdint>

// ---------------------------------------------------------------------------
// LSTM  B=64 T=512 I=H=1024
// Phase A: pack weights -> bf16 gate-INTERLEAVED transposes (n' = h*4+gate)
// Phase B: xproj GEMM, epilogue writes [t][bid][b][32]
// Phase C: persistent recurrence, 128 blocks x 8 H-cols, R6 tail structure.
//   R8 change (L2-shared h broadcast):
//   - h loads are NORMAL CACHED loads: the 16 blocks/XCD pull each h line
//     from LLC once and share it via their XCD L2 (16 MB/step -> 1 MB/step
//     of LLC fabric traffic; most reads at L2 latency)
//   - staleness handled by ONE agent-acquire fence (buffer_inv sc1) per
//     block per step, after poll success (poll's implicit vmcnt(0) makes
//     the fence's waitcnt free); pre-loop fence covers t=0
//   - h publish stays sc1 write-through (no wbl2 anywhere)
// ---------------------------------------------------------------------------

typedef __bf16 bf16_t;
typedef __bf16 bf16x8 __attribute__((ext_vector_type(8)));
typedef __bf16 bf16x4 __attribute__((ext_vector_type(4)));
typedef __bf16 bf16x2 __attribute__((ext_vector_type(2)));
typedef float  f32x4  __attribute__((ext_vector_type(4)));
typedef float  f32x2  __attribute__((ext_vector_type(2)));

#define MFMA16(a, b, c) __builtin_amdgcn_mfma_f32_16x16x32_bf16((a), (b), (c), 0, 0, 0)

// ---- problem constants ----
#define BB   64          // batch
#define TT   512         // time steps
#define HH   1024        // hidden = input
#define NBLK 128         // recurrent blocks (8 H-cols each)

// ---- workspace layout (bytes) ----
#define XPROJ_OFF  0ull                               // [T][128][64][32] bf16 = 256 MB
#define WX_OFF     268435456ull                       // Wx^T interleaved [4096][1024] bf16
#define WH_OFF     (WX_OFF + 8388608ull)              // Wh^T interleaved [4096][1024] bf16
#define BC_OFF     (WH_OFF + 8388608ull)              // bias interleaved f32[4096]
#define HB_OFF     (BC_OFF + 16384ull)                // h double buffer 2*64*1024 bf16
#define BAR_OFF    (HB_OFF + 262144ull)               // arrival array [NBLK] u32

__device__ __forceinline__ float fsig(float x) {
    return 1.0f / (1.0f + __expf(-x));
}
__device__ __forceinline__ float ftanh(float x) {
    return 1.0f - 2.0f / (__expf(2.0f * x) + 1.0f);
}

// ---------------------------------------------------------------------------
// Transpose-pack: src fp32 [1024 k][1024 h] -> dst bf16 row n' = h*4 + gate.
// ---------------------------------------------------------------------------
__global__ void transpose_pack(const float* __restrict__ s0, const float* __restrict__ s1,
                               const float* __restrict__ s2, const float* __restrict__ s3,
                               const float* __restrict__ s4, const float* __restrict__ s5,
                               const float* __restrict__ s6, const float* __restrict__ s7,
                               bf16_t* __restrict__ wxt, bf16_t* __restrict__ wht) {
    __shared__ float tile[64][65];
    const int z = blockIdx.z;
    const float* src = (z == 0) ? s0 : (z == 1) ? s1 : (z == 2) ? s2 : (z == 3) ? s3
                      : (z == 4) ? s4 : (z == 5) ? s5 : (z == 6) ? s6 : s7;
    bf16_t* dst = (z < 4) ? wxt : wht;
    const int gate = z & 3;
    const int k0 = blockIdx.x * 64, h0 = blockIdx.y * 64;
    const int t = threadIdx.x;
#pragma unroll
    for (int i = 0; i < 16; ++i) {
        int kk = (t >> 6) * 16 + i, hh = t & 63;
        tile[kk][hh] = src[(size_t)(k0 + kk) * 1024 + h0 + hh];
    }
    __syncthreads();
#pragma unroll
    for (int i = 0; i < 16; ++i) {
        int hh = (t >> 6) * 16 + i, kk = t & 63;
        dst[(size_t)((h0 + hh) * 4 + gate) * 1024 + k0 + kk] = (bf16_t)tile[kk][hh];
    }
}

__global__ void pack_bias(const float* __restrict__ bi, const float* __restrict__ bf_,
                          const float* __restrict__ bg, const float* __restrict__ bo,
                          float* __restrict__ bc) {
    int n = blockIdx.x * 256 + threadIdx.x;   // 0..4095 = h*4 + gate
    int g = n & 3, h = n >> 2;
    const float* s = (g == 0) ? bi : (g == 1) ? bf_ : (g == 2) ? bg : bo;
    bc[n] = s[h];
}

// ---------------------------------------------------------------------------
// Phase B GEMM over interleaved n'. Epilogue -> xp[t][n'>>5][b][n'&31].
// ---------------------------------------------------------------------------
__global__ __launch_bounds__(256, 2) void gemm_xproj(
    const float* __restrict__ x, const bf16_t* __restrict__ wx,
    const float* __restrict__ bc, bf16_t* __restrict__ xp) {
    __shared__ bf16_t Als[128][72];
    __shared__ bf16_t Bls[128][72];
    const int tid = threadIdx.x;
    const int n0 = blockIdx.x * 128, m0 = blockIdx.y * 128;
    const int lane = tid & 63, w = tid >> 6;
    const int wm = w >> 1, wn = w & 1;
    const int col = lane & 15, quad = lane >> 4;
    const int rowA = tid >> 4, ksegA = (tid & 15) * 4;
    const int rowB = tid >> 3, chunkB = tid & 7;
    f32x4 acc[4][4] = {};

    for (int kt = 0; kt < 16; ++kt) {
        const int k0 = kt * 64;
        __syncthreads();
#pragma unroll
        for (int i = 0; i < 8; ++i) {
            int r = rowA + i * 16;
            float4 v = *(const float4*)&x[(size_t)(m0 + r) * 1024 + k0 + ksegA];
            bf16x4 pv = { (bf16_t)v.x, (bf16_t)v.y, (bf16_t)v.z, (bf16_t)v.w };
            *(bf16x4*)&Als[r][ksegA] = pv;
        }
#pragma unroll
        for (int i = 0; i < 4; ++i) {
            int r = rowB + i * 32;
            *(bf16x8*)&Bls[r][chunkB * 8] =
                *(const bf16x8*)&wx[(size_t)(n0 + r) * 1024 + k0 + chunkB * 8];
        }
        __syncthreads();
#pragma unroll
        for (int kq = 0; kq < 64; kq += 32) {
            bf16x8 a[4], b[4];
#pragma unroll
            for (int s = 0; s < 4; ++s) {
                a[s] = *(const bf16x8*)&Als[wm * 64 + s * 16 + col][kq + quad * 8];
                b[s] = *(const bf16x8*)&Bls[wn * 64 + s * 16 + col][kq + quad * 8];
            }
#pragma unroll
            for (int sm = 0; sm < 4; ++sm)
#pragma unroll
                for (int sn = 0; sn < 4; ++sn)
                    acc[sm][sn] = MFMA16(a[sm], b[sn], acc[sm][sn]);
        }
    }
#pragma unroll
    for (int sm = 0; sm < 4; ++sm) {
        int mbase = m0 + wm * 64 + sm * 16 + quad * 4;
#pragma unroll
        for (int sn = 0; sn < 4; ++sn) {
            int n = n0 + wn * 64 + sn * 16 + col;
            float bias = bc[n];
            int bidr = n >> 5, off = n & 31;
#pragma unroll
            for (int reg = 0; reg < 4; ++reg) {
                int mm = mbase + reg;
                int b = mm >> 9, t = mm & 511;
                xp[((size_t)(t * 128 + bidr) * 64 + b) * 32 + off] =
                    (bf16_t)(acc[sm][sn][reg] + bias);
            }
        }
    }
}

// ---------------------------------------------------------------------------
// Phase C: persistent recurrence, 128 blocks x 8 H-cols.
// h broadcast through per-XCD L2 (cached loads) + one buffer_inv per step.
// ---------------------------------------------------------------------------
__global__ __launch_bounds__(256, 1) void lstm_rec(
    const bf16_t* __restrict__ xproj, const bf16_t* __restrict__ whc,
    bf16_t* __restrict__ hbuf, float* __restrict__ out,
    unsigned int* __restrict__ bar) {
    __shared__ bf16_t wh2[128][32][8];   // 64 KB, k-major
    __shared__ float  gl[64][37];        // gate scratch
    const int tid = threadIdx.x;
    const int bid = blockIdx.x;

    // stage Wh slice: n'off r = tid>>3 (0..31), k-chunk seg = tid&7
    {
        int r = tid >> 3, seg = tid & 7;
        const bf16_t* src = whc + (size_t)(bid * 32 + r) * 1024;
#pragma unroll
        for (int j = 0; j < 16; ++j) {
            int k = seg * 128 + j * 8;
            *(bf16x8*)&wh2[k >> 3][r][0] = *(const bf16x8*)&src[k];
        }
    }
    // one-time acquire: t=0 h (memset data) must not be served stale from
    // L1/L2 of a previous dispatch's lines
    __builtin_amdgcn_fence(__ATOMIC_ACQUIRE, "agent");
    __syncthreads();

    const int w = tid >> 6, lane = tid & 63;
    const int col = lane & 15, quad = lane >> 4;
    const int rowA = w * 16 + col;        // A-operand batch row
    const int bb0  = w * 16 + quad * 4;   // C-layout batch row base
    const int b2 = tid >> 2;              // activation batch (0..63)
    const int c2 = (tid & 3) * 2;         // activation col pair base (0,2,4,6)
    const int hcol = bid * 8 + c2;

    float cs0 = 0.0f, cs1 = 0.0f;
    float* hseq = out;                          // [64][512][1024]
    float* hT = out + (size_t)BB * TT * HH;     // [64][1024]
    float* cT = hT + BB * HH;                   // [64][1024]

    // xproj prefetch: ONE coalesced 16B load per thread
    bf16x8 xq = *(const bf16x8*)&xproj[((size_t)bid * 64 + b2) * 32 + c2 * 4];

    for (int t = 0; t < TT; ++t) {
        const bf16_t* hprev = hbuf + (size_t)(t & 1) * (BB * HH);
        bf16_t* hnext = hbuf + (size_t)((t + 1) & 1) * (BB * HH);

        // --- h gather: CACHED loads; freshness guaranteed by the per-step
        // buffer_inv executed after the previous step's poll ---
        const bf16_t* hbase = hprev + (size_t)rowA * 1024 + quad * 8;
        f32x4 acc0 = {0.f, 0.f, 0.f, 0.f};
        f32x4 acc1 = {0.f, 0.f, 0.f, 0.f};
        bf16x8 af0[8], af1[8];   // two 8-chunk buffers: <=64 VGPRs in flight

#define LDH(arr, i, o) asm volatile("global_load_dwordx4 %0, %1, off offset:" o \
                                    : "=v"(arr[i]) : "v"(hbase))
#define MFMA8(buf, kqb)                                                        \
    _Pragma("unroll")                                                          \
    for (int j = 0; j < 8; ++j) {                                              \
        bf16x8 b0 = *(const bf16x8*)&wh2[((kqb) + j) * 4 + quad][col][0];      \
        bf16x8 b1 = *(const bf16x8*)&wh2[((kqb) + j) * 4 + quad][16 + col][0]; \
        acc0 = MFMA16(buf[j], b0, acc0);                                       \
        acc1 = MFMA16(buf[j], b1, acc1);                                       \
    }

        // chunk0 (k 0..255) + chunk1 (k 256..511)
        LDH(af0, 0, "0");    LDH(af0, 1, "64");   LDH(af0, 2, "128");  LDH(af0, 3, "192");
        LDH(af0, 4, "256");  LDH(af0, 5, "320");  LDH(af0, 6, "384");  LDH(af0, 7, "448");
        LDH(af1, 0, "512");  LDH(af1, 1, "576");  LDH(af1, 2, "640");  LDH(af1, 3, "704");
        LDH(af1, 4, "768");  LDH(af1, 5, "832");  LDH(af1, 6, "896");  LDH(af1, 7, "960");
        asm volatile("s_waitcnt vmcnt(8)" ::: "memory");   // chunk0 ready
        __builtin_amdgcn_sched_barrier(0);
        MFMA8(af0, 0)
        // chunk2 into af0 (freed)
        LDH(af0, 0, "1024"); LDH(af0, 1, "1088"); LDH(af0, 2, "1152"); LDH(af0, 3, "1216");
        LDH(af0, 4, "1280"); LDH(af0, 5, "1344"); LDH(af0, 6, "1408"); LDH(af0, 7, "1472");
        asm volatile("s_waitcnt vmcnt(8)" ::: "memory");   // chunk1 ready
        __builtin_amdgcn_sched_barrier(0);
        MFMA8(af1, 8)
        // chunk3 into af1 (freed)
        LDH(af1, 0, "1536"); LDH(af1, 1, "1600"); LDH(af1, 2, "1664"); LDH(af1, 3, "1728");
        LDH(af1, 4, "1792"); LDH(af1, 5, "1856"); LDH(af1, 6, "1920"); LDH(af1, 7, "1984");
        asm volatile("s_waitcnt vmcnt(8)" ::: "memory");   // chunk2 ready
        __builtin_amdgcn_sched_barrier(0);
        MFMA8(af0, 16)
        asm volatile("s_waitcnt vmcnt(0)" ::: "memory");   // chunk3 ready
        __builtin_amdgcn_sched_barrier(0);
        MFMA8(af1, 24)
#undef MFMA8
#undef LDH

        // gates -> LDS. Rows [16w,16w+16) written AND read by wave w only.
#pragma unroll
        for (int reg = 0; reg < 4; ++reg) {
            gl[bb0 + reg][col]      = acc0[reg];
            gl[bb0 + reg][16 + col] = acc1[reg];
        }

        // --- activations: batch b2, interleaved gate cols c2*4 .. c2*4+7 ---
        float il  = gl[b2][c2 * 4 + 0] + (float)xq[0];
        float fl_ = gl[b2][c2 * 4 + 1] + (float)xq[1];
        float ggl = gl[b2][c2 * 4 + 2] + (float)xq[2];
        float ol  = gl[b2][c2 * 4 + 3] + (float)xq[3];
        float ih  = gl[b2][c2 * 4 + 4] + (float)xq[4];
        float fh  = gl[b2][c2 * 4 + 5] + (float)xq[5];
        float gh  = gl[b2][c2 * 4 + 6] + (float)xq[6];
        float oh  = gl[b2][c2 * 4 + 7] + (float)xq[7];
        cs0 = fsig(fl_) * cs0 + fsig(il) * ftanh(ggl);
        cs1 = fsig(fh) * cs1 + fsig(ih) * ftanh(gh);
        float hv0 = fsig(ol) * ftanh(cs0);
        float hv1 = fsig(oh) * ftanh(cs1);
        f32x2 hv2 = { hv0, hv1 };

        if (t == TT - 1) {
            __builtin_nontemporal_store(hv2, (f32x2*)&hseq[(size_t)b2 * (TT * HH) + t * HH + hcol]);
            __builtin_nontemporal_store(hv2, (f32x2*)&hT[(size_t)b2 * HH + hcol]);
            f32x2 cv2 = { cs0, cs1 };
            __builtin_nontemporal_store(cv2, (f32x2*)&cT[(size_t)b2 * HH + hcol]);
            break;
        }

        // --- R6 tail: publish -> vmcnt(0) -> sync -> flag -> hseq/xq -> poll ---
        bf16x2 hb2 = { (bf16_t)hv0, (bf16_t)hv1 };
        unsigned hpk = __builtin_bit_cast(unsigned, hb2);
        __hip_atomic_store((unsigned*)(hnext + (size_t)b2 * HH + hcol), hpk,
                           __ATOMIC_RELAXED, __HIP_MEMORY_SCOPE_AGENT);
        asm volatile("s_waitcnt vmcnt(0)" ::: "memory");   // h at LLC
        __syncthreads();                                    // all 4 waves done

        const unsigned tgt = (unsigned)(t + 1);
        if (w == 0 && lane == 0)
            __hip_atomic_store(&bar[bid], tgt, __ATOMIC_RELAXED,
                               __HIP_MEMORY_SCOPE_AGENT);
        // long-latency, non-critical ops under the poll window:
        __builtin_nontemporal_store(hv2, (f32x2*)&hseq[(size_t)b2 * (TT * HH) + t * HH + hcol]);
        xq = *(const bf16x8*)&xproj[((size_t)((t + 1) * 128 + bid) * 64 + b2) * 32 + c2 * 4];

        if (w == 0) {
            // direct poll-all: lane l watches bar[l], bar[64+l]
            for (;;) {
                unsigned v0 = __hip_atomic_load(bar + lane, __ATOMIC_RELAXED,
                                                __HIP_MEMORY_SCOPE_AGENT);
                unsigned v1 = __hip_atomic_load(bar + 64 + lane, __ATOMIC_RELAXED,
                                                __HIP_MEMORY_SCOPE_AGENT);
                if (__all((v0 >= tgt) & (v1 >= tgt))) break;
                __builtin_amdgcn_s_sleep(1);
            }
            // acquire: ONE buffer_inv per step. The poll's implicit vmcnt(0)
            // already drained everything, so the fence's waitcnt is free.
            // Invalidate L1 + stale non-local L2 h lines -> cached h loads
            // next step are guaranteed fresh (pulled from LLC once per XCD).
            __builtin_amdgcn_fence(__ATOMIC_ACQUIRE, "agent");
            __builtin_amdgcn_sched_barrier(0);
        }
        __syncthreads();   // releases waves 1..3; orders next h loads after inv
    }
}

// ---------------------------------------------------------------------------
extern "C" void kernel_launch(void* const* d_in, const int* in_sizes, int n_in,
                              void* d_out, int out_size, void* d_ws, size_t ws_size,
                              hipStream_t stream) {
    (void)in_sizes; (void)n_in; (void)out_size; (void)ws_size;
    const float* x   = (const float*)d_in[0];
    const float* wii = (const float*)d_in[1];
    const float* whi = (const float*)d_in[2];
    const float* bi  = (const float*)d_in[3];
    const float* wif = (const float*)d_in[4];
    const float* whf = (const float*)d_in[5];
    const float* bfb = (const float*)d_in[6];
    const float* wig = (const float*)d_in[7];
    const float* whg = (const float*)d_in[8];
    const float* bg  = (const float*)d_in[9];
    const float* wio = (const float*)d_in[10];
    const float* who = (const float*)d_in[11];
    const float* bo  = (const float*)d_in[12];

    char* ws = (char*)d_ws;
    bf16_t*   xp   = (bf16_t*)(ws + XPROJ_OFF);
    bf16_t*   wxt  = (bf16_t*)(ws + WX_OFF);
    bf16_t*   wht  = (bf16_t*)(ws + WH_OFF);
    float*    bc   = (float*)(ws + BC_OFF);
    bf16_t*   hbuf = (bf16_t*)(ws + HB_OFF);
    unsigned* bar  = (unsigned*)(ws + BAR_OFF);

    // zero h double-buffer + arrival array (contiguous region)
    (void)hipMemsetAsync(hbuf, 0, 262144 + 4096, stream);

    transpose_pack<<<dim3(16, 16, 8), 256, 0, stream>>>(wii, wif, wig, wio,
                                                        whi, whf, whg, who, wxt, wht);
    pack_bias<<<16, 256, 0, stream>>>(bi, bfb, bg, bo, bc);
    gemm_xproj<<<dim3(32, 256), 256, 0, stream>>>(x, wxt, bc, xp);
    lstm_rec<<<NBLK, 256, 0, stream>>>(xp, wht, hbuf, (float*)d_out, bar);
}

// Round 9
// 3924.731 us; speedup vs baseline: 1.1030x; 1.1030x over previous
//
#include <hip/hip_runtime.h>
#include <cstddef>
#include <cstdint>

// ---------------------------------------------------------------------------
// LSTM  B=64 T=512 I=H=1024
// Phase A: pack weights -> bf16 gate-INTERLEAVED transposes (n' = h*4+gate)
// Phase B: xproj GEMM, epilogue writes [t][bid][b][32]
// Phase C: persistent recurrence, 128 blocks x 8 H-cols, R6 structure
//          (fence-free: sc1 write-through publish + sc0/sc1 bypass loads,
//           direct poll-all barrier, counted-vmcnt chunked h pipeline).
//   R9 changes (LLC queue-spreading):
//   - bid-staggered chunk order: block bid streams h chunks in order
//     (bid&3, bid&3+1, ...) mod 4 -> the simultaneous 16 MB burst spreads
//     across all four quarters of the LLC bank space instead of piling
//     onto k=0 first (K-sum reorder: numerically benign)
//   - s_sleep(2) poll backoff: halves flag-line contention, which also
//     delays flag-WRITE visibility when polled at s_sleep(1) rate
// ---------------------------------------------------------------------------

typedef __bf16 bf16_t;
typedef __bf16 bf16x8 __attribute__((ext_vector_type(8)));
typedef __bf16 bf16x4 __attribute__((ext_vector_type(4)));
typedef __bf16 bf16x2 __attribute__((ext_vector_type(2)));
typedef float  f32x4  __attribute__((ext_vector_type(4)));
typedef float  f32x2  __attribute__((ext_vector_type(2)));

#define MFMA16(a, b, c) __builtin_amdgcn_mfma_f32_16x16x32_bf16((a), (b), (c), 0, 0, 0)

// ---- problem constants ----
#define BB   64          // batch
#define TT   512         // time steps
#define HH   1024        // hidden = input
#define NBLK 128         // recurrent blocks (8 H-cols each)

// ---- workspace layout (bytes) ----
#define XPROJ_OFF  0ull                               // [T][128][64][32] bf16 = 256 MB
#define WX_OFF     268435456ull                       // Wx^T interleaved [4096][1024] bf16
#define WH_OFF     (WX_OFF + 8388608ull)              // Wh^T interleaved [4096][1024] bf16
#define BC_OFF     (WH_OFF + 8388608ull)              // bias interleaved f32[4096]
#define HB_OFF     (BC_OFF + 16384ull)                // h double buffer 2*64*1024 bf16
#define BAR_OFF    (HB_OFF + 262144ull)               // arrival array [NBLK] u32

__device__ __forceinline__ float fsig(float x) {
    return 1.0f / (1.0f + __expf(-x));
}
__device__ __forceinline__ float ftanh(float x) {
    return 1.0f - 2.0f / (__expf(2.0f * x) + 1.0f);
}

// ---------------------------------------------------------------------------
// Transpose-pack: src fp32 [1024 k][1024 h] -> dst bf16 row n' = h*4 + gate.
// ---------------------------------------------------------------------------
__global__ void transpose_pack(const float* __restrict__ s0, const float* __restrict__ s1,
                               const float* __restrict__ s2, const float* __restrict__ s3,
                               const float* __restrict__ s4, const float* __restrict__ s5,
                               const float* __restrict__ s6, const float* __restrict__ s7,
                               bf16_t* __restrict__ wxt, bf16_t* __restrict__ wht) {
    __shared__ float tile[64][65];
    const int z = blockIdx.z;
    const float* src = (z == 0) ? s0 : (z == 1) ? s1 : (z == 2) ? s2 : (z == 3) ? s3
                      : (z == 4) ? s4 : (z == 5) ? s5 : (z == 6) ? s6 : s7;
    bf16_t* dst = (z < 4) ? wxt : wht;
    const int gate = z & 3;
    const int k0 = blockIdx.x * 64, h0 = blockIdx.y * 64;
    const int t = threadIdx.x;
#pragma unroll
    for (int i = 0; i < 16; ++i) {
        int kk = (t >> 6) * 16 + i, hh = t & 63;
        tile[kk][hh] = src[(size_t)(k0 + kk) * 1024 + h0 + hh];
    }
    __syncthreads();
#pragma unroll
    for (int i = 0; i < 16; ++i) {
        int hh = (t >> 6) * 16 + i, kk = t & 63;
        dst[(size_t)((h0 + hh) * 4 + gate) * 1024 + k0 + kk] = (bf16_t)tile[kk][hh];
    }
}

__global__ void pack_bias(const float* __restrict__ bi, const float* __restrict__ bf_,
                          const float* __restrict__ bg, const float* __restrict__ bo,
                          float* __restrict__ bc) {
    int n = blockIdx.x * 256 + threadIdx.x;   // 0..4095 = h*4 + gate
    int g = n & 3, h = n >> 2;
    const float* s = (g == 0) ? bi : (g == 1) ? bf_ : (g == 2) ? bg : bo;
    bc[n] = s[h];
}

// ---------------------------------------------------------------------------
// Phase B GEMM over interleaved n'. Epilogue -> xp[t][n'>>5][b][n'&31].
// ---------------------------------------------------------------------------
__global__ __launch_bounds__(256, 2) void gemm_xproj(
    const float* __restrict__ x, const bf16_t* __restrict__ wx,
    const float* __restrict__ bc, bf16_t* __restrict__ xp) {
    __shared__ bf16_t Als[128][72];
    __shared__ bf16_t Bls[128][72];
    const int tid = threadIdx.x;
    const int n0 = blockIdx.x * 128, m0 = blockIdx.y * 128;
    const int lane = tid & 63, w = tid >> 6;
    const int wm = w >> 1, wn = w & 1;
    const int col = lane & 15, quad = lane >> 4;
    const int rowA = tid >> 4, ksegA = (tid & 15) * 4;
    const int rowB = tid >> 3, chunkB = tid & 7;
    f32x4 acc[4][4] = {};

    for (int kt = 0; kt < 16; ++kt) {
        const int k0 = kt * 64;
        __syncthreads();
#pragma unroll
        for (int i = 0; i < 8; ++i) {
            int r = rowA + i * 16;
            float4 v = *(const float4*)&x[(size_t)(m0 + r) * 1024 + k0 + ksegA];
            bf16x4 pv = { (bf16_t)v.x, (bf16_t)v.y, (bf16_t)v.z, (bf16_t)v.w };
            *(bf16x4*)&Als[r][ksegA] = pv;
        }
#pragma unroll
        for (int i = 0; i < 4; ++i) {
            int r = rowB + i * 32;
            *(bf16x8*)&Bls[r][chunkB * 8] =
                *(const bf16x8*)&wx[(size_t)(n0 + r) * 1024 + k0 + chunkB * 8];
        }
        __syncthreads();
#pragma unroll
        for (int kq = 0; kq < 64; kq += 32) {
            bf16x8 a[4], b[4];
#pragma unroll
            for (int s = 0; s < 4; ++s) {
                a[s] = *(const bf16x8*)&Als[wm * 64 + s * 16 + col][kq + quad * 8];
                b[s] = *(const bf16x8*)&Bls[wn * 64 + s * 16 + col][kq + quad * 8];
            }
#pragma unroll
            for (int sm = 0; sm < 4; ++sm)
#pragma unroll
                for (int sn = 0; sn < 4; ++sn)
                    acc[sm][sn] = MFMA16(a[sm], b[sn], acc[sm][sn]);
        }
    }
#pragma unroll
    for (int sm = 0; sm < 4; ++sm) {
        int mbase = m0 + wm * 64 + sm * 16 + quad * 4;
#pragma unroll
        for (int sn = 0; sn < 4; ++sn) {
            int n = n0 + wn * 64 + sn * 16 + col;
            float bias = bc[n];
            int bidr = n >> 5, off = n & 31;
#pragma unroll
            for (int reg = 0; reg < 4; ++reg) {
                int mm = mbase + reg;
                int b = mm >> 9, t = mm & 511;
                xp[((size_t)(t * 128 + bidr) * 64 + b) * 32 + off] =
                    (bf16_t)(acc[sm][sn][reg] + bias);
            }
        }
    }
}

// ---------------------------------------------------------------------------
// Phase C: persistent recurrence, fence-free, 128 blocks x 8 H-cols.
// h loads: sc0/sc1 bypass from LLC, bid-staggered chunk order.
// ---------------------------------------------------------------------------
__global__ __launch_bounds__(256, 1) void lstm_rec(
    const bf16_t* __restrict__ xproj, const bf16_t* __restrict__ whc,
    bf16_t* __restrict__ hbuf, float* __restrict__ out,
    unsigned int* __restrict__ bar) {
    __shared__ bf16_t wh2[128][32][8];   // 64 KB, k-major
    __shared__ float  gl[64][37];        // gate scratch
    const int tid = threadIdx.x;
    const int bid = blockIdx.x;

    // stage Wh slice: n'off r = tid>>3 (0..31), k-chunk seg = tid&7
    {
        int r = tid >> 3, seg = tid & 7;
        const bf16_t* src = whc + (size_t)(bid * 32 + r) * 1024;
#pragma unroll
        for (int j = 0; j < 16; ++j) {
            int k = seg * 128 + j * 8;
            *(bf16x8*)&wh2[k >> 3][r][0] = *(const bf16x8*)&src[k];
        }
    }
    __syncthreads();

    const int w = tid >> 6, lane = tid & 63;
    const int col = lane & 15, quad = lane >> 4;
    const int rowA = w * 16 + col;        // A-operand batch row
    const int bb0  = w * 16 + quad * 4;   // C-layout batch row base
    const int b2 = tid >> 2;              // activation batch (0..63)
    const int c2 = (tid & 3) * 2;         // activation col pair base (0,2,4,6)
    const int hcol = bid * 8 + c2;

    // staggered chunk ids: block bid starts its h stream at quarter (bid&3)
    const int cc0 = bid & 3, cc1 = (bid + 1) & 3, cc2 = (bid + 2) & 3, cc3 = (bid + 3) & 3;
    const int kq0 = cc0 * 8, kq1 = cc1 * 8, kq2 = cc2 * 8, kq3 = cc3 * 8;

    float cs0 = 0.0f, cs1 = 0.0f;
    float* hseq = out;                          // [64][512][1024]
    float* hT = out + (size_t)BB * TT * HH;     // [64][1024]
    float* cT = hT + BB * HH;                   // [64][1024]

    // xproj prefetch: ONE coalesced 16B load per thread
    bf16x8 xq = *(const bf16x8*)&xproj[((size_t)bid * 64 + b2) * 32 + c2 * 4];

    for (int t = 0; t < TT; ++t) {
        const bf16_t* hprev = hbuf + (size_t)(t & 1) * (BB * HH);
        bf16_t* hnext = hbuf + (size_t)((t + 1) & 1) * (BB * HH);

        // per-chunk base pointers (chunk c covers k in [c*256, c*256+256))
        const bf16_t* hbase = hprev + (size_t)rowA * 1024 + quad * 8;
        const bf16_t* hb0 = hbase + cc0 * 256;
        const bf16_t* hb1 = hbase + cc1 * 256;
        const bf16_t* hb2c = hbase + cc2 * 256;
        const bf16_t* hb3 = hbase + cc3 * 256;

        f32x4 acc0 = {0.f, 0.f, 0.f, 0.f};
        f32x4 acc1 = {0.f, 0.f, 0.f, 0.f};
        bf16x8 af0[8], af1[8];   // two 8-chunk buffers: <=64 VGPRs in flight

#define LDH(arr, i, base, o) asm volatile("global_load_dwordx4 %0, %1, off offset:" o " sc0 sc1" \
                                          : "=v"(arr[i]) : "v"(base))
#define LD8(arr, base)                                                   \
    LDH(arr, 0, base, "0");   LDH(arr, 1, base, "64");                   \
    LDH(arr, 2, base, "128"); LDH(arr, 3, base, "192");                  \
    LDH(arr, 4, base, "256"); LDH(arr, 5, base, "320");                  \
    LDH(arr, 6, base, "384"); LDH(arr, 7, base, "448")
#define MFMA8(buf, kqb)                                                        \
    _Pragma("unroll")                                                          \
    for (int j = 0; j < 8; ++j) {                                              \
        bf16x8 b0 = *(const bf16x8*)&wh2[((kqb) + j) * 4 + quad][col][0];      \
        bf16x8 b1 = *(const bf16x8*)&wh2[((kqb) + j) * 4 + quad][16 + col][0]; \
        acc0 = MFMA16(buf[j], b0, acc0);                                       \
        acc1 = MFMA16(buf[j], b1, acc1);                                       \
    }

        LD8(af0, hb0);                 // chunk cc0
        LD8(af1, hb1);                 // chunk cc1
        asm volatile("s_waitcnt vmcnt(8)" ::: "memory");   // cc0 ready
        __builtin_amdgcn_sched_barrier(0);
        MFMA8(af0, kq0)
        LD8(af0, hb2c);                // chunk cc2 into af0 (freed)
        asm volatile("s_waitcnt vmcnt(8)" ::: "memory");   // cc1 ready
        __builtin_amdgcn_sched_barrier(0);
        MFMA8(af1, kq1)
        LD8(af1, hb3);                 // chunk cc3 into af1 (freed)
        asm volatile("s_waitcnt vmcnt(8)" ::: "memory");   // cc2 ready
        __builtin_amdgcn_sched_barrier(0);
        MFMA8(af0, kq2)
        asm volatile("s_waitcnt vmcnt(0)" ::: "memory");   // cc3 ready
        __builtin_amdgcn_sched_barrier(0);
        MFMA8(af1, kq3)
#undef MFMA8
#undef LD8
#undef LDH

        // gates -> LDS. Rows [16w,16w+16) written AND read by wave w only.
#pragma unroll
        for (int reg = 0; reg < 4; ++reg) {
            gl[bb0 + reg][col]      = acc0[reg];
            gl[bb0 + reg][16 + col] = acc1[reg];
        }

        // --- activations: batch b2, interleaved gate cols c2*4 .. c2*4+7 ---
        float il  = gl[b2][c2 * 4 + 0] + (float)xq[0];
        float fl_ = gl[b2][c2 * 4 + 1] + (float)xq[1];
        float ggl = gl[b2][c2 * 4 + 2] + (float)xq[2];
        float ol  = gl[b2][c2 * 4 + 3] + (float)xq[3];
        float ih  = gl[b2][c2 * 4 + 4] + (float)xq[4];
        float fh  = gl[b2][c2 * 4 + 5] + (float)xq[5];
        float gh  = gl[b2][c2 * 4 + 6] + (float)xq[6];
        float oh  = gl[b2][c2 * 4 + 7] + (float)xq[7];
        cs0 = fsig(fl_) * cs0 + fsig(il) * ftanh(ggl);
        cs1 = fsig(fh) * cs1 + fsig(ih) * ftanh(gh);
        float hv0 = fsig(ol) * ftanh(cs0);
        float hv1 = fsig(oh) * ftanh(cs1);
        f32x2 hv2 = { hv0, hv1 };

        if (t == TT - 1) {
            __builtin_nontemporal_store(hv2, (f32x2*)&hseq[(size_t)b2 * (TT * HH) + t * HH + hcol]);
            __builtin_nontemporal_store(hv2, (f32x2*)&hT[(size_t)b2 * HH + hcol]);
            f32x2 cv2 = { cs0, cs1 };
            __builtin_nontemporal_store(cv2, (f32x2*)&cT[(size_t)b2 * HH + hcol]);
            break;
        }

        // --- R6 tail: publish -> vmcnt(0) -> sync -> flag -> hseq/xq -> poll ---
        bf16x2 hb2 = { (bf16_t)hv0, (bf16_t)hv1 };
        unsigned hpk = __builtin_bit_cast(unsigned, hb2);
        __hip_atomic_store((unsigned*)(hnext + (size_t)b2 * HH + hcol), hpk,
                           __ATOMIC_RELAXED, __HIP_MEMORY_SCOPE_AGENT);
        asm volatile("s_waitcnt vmcnt(0)" ::: "memory");   // h at LLC
        __syncthreads();                                    // all 4 waves done

        const unsigned tgt = (unsigned)(t + 1);
        if (w == 0 && lane == 0)
            __hip_atomic_store(&bar[bid], tgt, __ATOMIC_RELAXED,
                               __HIP_MEMORY_SCOPE_AGENT);
        // long-latency, non-critical ops under the poll window:
        __builtin_nontemporal_store(hv2, (f32x2*)&hseq[(size_t)b2 * (TT * HH) + t * HH + hcol]);
        xq = *(const bf16x8*)&xproj[((size_t)((t + 1) * 128 + bid) * 64 + b2) * 32 + c2 * 4];

        if (w == 0) {
            // direct poll-all: lane l watches bar[l], bar[64+l]
            for (;;) {
                unsigned v0 = __hip_atomic_load(bar + lane, __ATOMIC_RELAXED,
                                                __HIP_MEMORY_SCOPE_AGENT);
                unsigned v1 = __hip_atomic_load(bar + 64 + lane, __ATOMIC_RELAXED,
                                                __HIP_MEMORY_SCOPE_AGENT);
                if (__all((v0 >= tgt) & (v1 >= tgt))) break;
                __builtin_amdgcn_s_sleep(2);
            }
        }
        __syncthreads();   // releases waves 1..3; orders next h loads after barrier
    }
}

// ---------------------------------------------------------------------------
extern "C" void kernel_launch(void* const* d_in, const int* in_sizes, int n_in,
                              void* d_out, int out_size, void* d_ws, size_t ws_size,
                              hipStream_t stream) {
    (void)in_sizes; (void)n_in; (void)out_size; (void)ws_size;
    const float* x   = (const float*)d_in[0];
    const float* wii = (const float*)d_in[1];
    const float* whi = (const float*)d_in[2];
    const float* bi  = (const float*)d_in[3];
    const float* wif = (const float*)d_in[4];
    const float* whf = (const float*)d_in[5];
    const float* bfb = (const float*)d_in[6];
    const float* wig = (const float*)d_in[7];
    const float* whg = (const float*)d_in[8];
    const float* bg  = (const float*)d_in[9];
    const float* wio = (const float*)d_in[10];
    const float* who = (const float*)d_in[11];
    const float* bo  = (const float*)d_in[12];

    char* ws = (char*)d_ws;
    bf16_t*   xp   = (bf16_t*)(ws + XPROJ_OFF);
    bf16_t*   wxt  = (bf16_t*)(ws + WX_OFF);
    bf16_t*   wht  = (bf16_t*)(ws + WH_OFF);
    float*    bc   = (float*)(ws + BC_OFF);
    bf16_t*   hbuf = (bf16_t*)(ws + HB_OFF);
    unsigned* bar  = (unsigned*)(ws + BAR_OFF);

    // zero h double-buffer + arrival array (contiguous region)
    (void)hipMemsetAsync(hbuf, 0, 262144 + 4096, stream);

    transpose_pack<<<dim3(16, 16, 8), 256, 0, stream>>>(wii, wif, wig, wio,
                                                        whi, whf, whg, who, wxt, wht);
    pack_bias<<<16, 256, 0, stream>>>(bi, bfb, bg, bo, bc);
    gemm_xproj<<<dim3(32, 256), 256, 0, stream>>>(x, wxt, bc, xp);
    lstm_rec<<<NBLK, 256, 0, stream>>>(xp, wht, hbuf, (float*)d_out, bar);
}